// Round 8
// baseline (156.943 us; speedup 1.0000x reference)
//
#include <hip/hip_runtime.h>

// 16-qubit, 2-layer circuit, batch 32.  Circuit = P*R1*P*R0 (P = CNOT-ring permutation).
// f(i) = i ^ (i>>1) ^ (bit0(i)?0xC000:0);  f^{-1} = suffix-xor cascade.
//
// R11: PER-PASS DIAGNOSTIC, reps {3,3,4}. R10 proved the XCD-local skip-fence
// works (profiled FETCH halved to ~16.8 MB = x only; profiled dur 88us) yet the
// bench stays ~104-105: every timed iteration is fully COLD (workspace
// re-poisoned, inputs restored), and ~23us/pass of cold cost is unexplained by
// any counter seen so far. R9's reps=2 left passes at <=44us, just under the
// 44-47us fill dispatches that flood top-5. reps {3,3,4} puts each pass at
// ~50-65us -> all three surface with per-pass dur/FETCH/WRITE/VALUBusy.
// Combined with R9 (reps=2 aggregate) this solves cold-vs-warm per pass.
// Math identical (bodies idempotent; pass2 ping-pongs ws->ws2); dur_us
// intentionally ~165us this round; reverting next round.

#define NT 256

__device__ __forceinline__ int fperm(int x) {
  int y = x ^ (x >> 1);
  y ^= (x & 1) ? 0xC000 : 0;
  return y & 0xFFFF;
}

__device__ __forceinline__ int finv16(int x) {
  int s = x;
  s ^= s >> 1; s ^= s >> 2; s ^= s >> 4; s ^= s >> 8;
  int b15 = ((s ^ (s >> 15)) & 1) << 15;
  return (s & 0x7FFF) | b15;
}

__device__ __forceinline__ int swz1(int l) { return l ^ ((l >> 4) & 31); }
__device__ __forceinline__ int swz2(int l) { return l ^ ((l >> 5) & 31); }

__device__ __forceinline__ void compute_gates(const float* __restrict__ th, float* gsh) {
  int tid = threadIdx.x;
  if (tid < 32) {
    int l = tid >> 4, q = tid & 15;
    float tx = th[l * 48 + q], ty = th[l * 48 + 16 + q], tz = th[l * 48 + 32 + q];
    float cx, sx, cy, sy, cz, sz;
    sincosf(0.5f * tx, &sx, &cx);
    sincosf(0.5f * ty, &sy, &cy);
    sincosf(0.5f * tz, &sz, &cz);
    float m00r = cy * cx, m00i =  sy * sx;
    float m01r = -sy * cx, m01i = -cy * sx;
    float m10r =  sy * cx, m10i = -cy * sx;
    float m11r =  cy * cx, m11i = -sy * sx;
    float* G = gsh + tid * 8;
    G[0] = cz * m00r + sz * m00i;  G[1] = cz * m00i - sz * m00r;
    G[2] = cz * m01r + sz * m01i;  G[3] = cz * m01i - sz * m01r;
    G[4] = cz * m10r - sz * m10i;  G[5] = cz * m10i + sz * m10r;
    G[6] = cz * m11r - sz * m11i;  G[7] = cz * m11i + sz * m11r;
  }
}

template <int MK, int SK, int N>
__device__ __forceinline__ void greg(float (&ar)[N], float (&ai)[N],
                                     const float* G, int c) {
  const float4* G4 = (const float4*)G;
  float4 r0 = G4[0], r1 = G4[1];
  bool sw = (c != 0);
  float h00r = sw ? r1.z : r0.x, h00i = sw ? r1.w : r0.y;
  float h01r = sw ? r1.x : r0.z, h01i = sw ? r1.y : r0.w;
  float h10r = sw ? r0.z : r1.x, h10i = sw ? r0.w : r1.y;
  float h11r = sw ? r0.x : r1.z, h11i = sw ? r0.y : r1.w;
  constexpr int PV = MK & (-MK);
#pragma unroll
  for (int k = 0; k < N; k++) {
    if (k & PV) continue;
    const int k2 = k ^ MK;
    const int p0 = __builtin_popcount(k & SK) & 1;
    const int ka = p0 ? k2 : k;
    const int kb = p0 ? k : k2;
    float xr = ar[ka], xi = ai[ka], yr = ar[kb], yi = ai[kb];
    ar[ka] = h00r * xr - h00i * xi + h01r * yr - h01i * yi;
    ai[ka] = h00r * xi + h00i * xr + h01r * yi + h01i * yr;
    ar[kb] = h10r * xr - h10i * xi + h11r * yr - h11i * yi;
    ai[kb] = h10r * xi + h10i * xr + h11r * yi + h11i * yr;
  }
}

// ====================== Phase bodies as device functions ======================

__device__ __forceinline__ void phaseA_body(int t, int bbase, int wb,
                                            const float* gsh,
                                            float* sre, float* sim,
                                            const float* __restrict__ xre,
                                            const float* __restrict__ xim,
                                            float2* __restrict__ ws) {
  float ar[16], ai[16];
  int base = bbase + (wb << 12);
  const float4* xr4 = (const float4*)(xre + base + (t << 4));
  const float4* xi4 = (const float4*)(xim + base + (t << 4));
#pragma unroll
  for (int q = 0; q < 4; q++) {
    float4 v = xr4[q]; ar[4*q] = v.x; ar[4*q+1] = v.y; ar[4*q+2] = v.z; ar[4*q+3] = v.w;
    float4 w = xi4[q]; ai[4*q] = w.x; ai[4*q+1] = w.y; ai[4*q+2] = w.z; ai[4*q+3] = w.w;
  }
  __syncthreads();   // gsh ready (and sre/sim free)
  greg<1, 1>(ar, ai, gsh + 15 * 8, 0);
  greg<2, 2>(ar, ai, gsh + 14 * 8, 0);
  greg<4, 4>(ar, ai, gsh + 13 * 8, 0);
  greg<8, 8>(ar, ai, gsh + 12 * 8, 0);
#pragma unroll
  for (int k = 0; k < 16; k++) { int s = swz1((t << 4) | k); sre[s] = ar[k]; sim[s] = ai[k]; }
  __syncthreads();
#pragma unroll
  for (int k = 0; k < 16; k++) {
    int s = swz1((t & 15) | (k << 4) | ((t >> 4) << 8));
    ar[k] = sre[s]; ai[k] = sim[s];
  }
  greg<1, 1>(ar, ai, gsh + 11 * 8, 0);
  greg<2, 2>(ar, ai, gsh + 10 * 8, 0);
  greg<4, 4>(ar, ai, gsh + 9 * 8, 0);
  greg<8, 8>(ar, ai, gsh + 8 * 8, 0);
#pragma unroll
  for (int k = 0; k < 16; k++) {
    int s = swz1((t & 15) | (k << 4) | ((t >> 4) << 8));
    sre[s] = ar[k]; sim[s] = ai[k];
  }
  __syncthreads();
#pragma unroll
  for (int k = 0; k < 16; k++) {
    int s = swz1(t | (k << 8)); ar[k] = sre[s]; ai[k] = sim[s];
  }
  greg<1, 1>(ar, ai, gsh + 7 * 8, 0);
  greg<2, 2>(ar, ai, gsh + 6 * 8, 0);
  greg<4, 4>(ar, ai, gsh + 5 * 8, 0);
  greg<8, 8>(ar, ai, gsh + 4 * 8, 0);
#pragma unroll
  for (int k = 0; k < 16; k++)
    ws[base + t + (k << 8)] = make_float2(ar[k], ai[k]);
}

__device__ __forceinline__ void phaseB_body(int t, int bbase, int wb,
                                            const float* gsh,
                                            float* sre, float* sim,
                                            const float2* __restrict__ wsi,
                                            float2* __restrict__ wso) {
  float ar[16], ai[16];
#pragma unroll
  for (int k = 0; k < 16; k++) {
    float2 v = wsi[bbase + t + (wb << 8) + (k << 12)];
    ar[k] = v.x; ai[k] = v.y;
  }
  int cA = (__popc(t) + __popc(wb)) & 1;   // parity of full bits 0..11
  greg<1, 1>(ar, ai, gsh + 3 * 8, 0);
  greg<2, 2>(ar, ai, gsh + 2 * 8, 0);
  greg<4, 4>(ar, ai, gsh + 1 * 8, 0);
  greg<8, 8>(ar, ai, gsh + 0 * 8, 0);
  greg<12, 7>(ar, ai, gsh + (16 + 0) * 8, cA);
  greg<6, 12>(ar, ai, gsh + (16 + 1) * 8, 0);
  greg<3, 14>(ar, ai, gsh + (16 + 2) * 8, 0);
  __syncthreads();   // sre/sim free
#pragma unroll
  for (int k = 0; k < 16; k++) {
    int s = swz2(t | (k << 8)); sre[s] = ar[k]; sim[s] = ai[k];
  }
  __syncthreads();
#pragma unroll
  for (int k = 0; k < 16; k++) {
    int s = swz2((k & 3) | (t << 2) | ((k >> 2) << 10));
    ar[k] = sre[s]; ai[k] = sim[s];
  }
  greg<13, 15>(ar, ai, gsh + (16 + 15) * 8, cA);
  greg<3, 14>(ar, ai, gsh + (16 + 14) * 8, cA);
#pragma unroll
  for (int k = 0; k < 16; k++) {
    int s = swz2((k & 3) | (t << 2) | ((k >> 2) << 10));
    sre[s] = ar[k]; sim[s] = ai[k];
  }
  __syncthreads();
#pragma unroll
  for (int k = 0; k < 16; k++) {
    int s = swz2((t & 1) | (k << 1) | ((t >> 1) << 5));
    ar[k] = sre[s]; ai[k] = sim[s];
  }
  {
    int cC = (__popc(t >> 1) + __popc(wb)) & 1;
    greg<3, 14>(ar, ai, gsh + (16 + 13) * 8, cC);
    greg<6, 12>(ar, ai, gsh + (16 + 12) * 8, cC);
    greg<12, 8>(ar, ai, gsh + (16 + 11) * 8, cC);
  }
#pragma unroll
  for (int k = 0; k < 16; k++) {
    int s = swz2((t & 1) | (k << 1) | ((t >> 1) << 5));
    sre[s] = ar[k]; sim[s] = ai[k];
  }
  __syncthreads();
#pragma unroll
  for (int k = 0; k < 16; k++) {
    int s = swz2((t & 15) | (k << 4) | ((t >> 4) << 8));
    ar[k] = sre[s]; ai[k] = sim[s];
  }
  {
    int cD = (__popc(t >> 4) + __popc(wb)) & 1;
    greg<3, 14>(ar, ai, gsh + (16 + 10) * 8, cD);
    greg<6, 12>(ar, ai, gsh + (16 + 9) * 8, cD);
    greg<12, 8>(ar, ai, gsh + (16 + 8) * 8, cD);
  }
#pragma unroll
  for (int k = 0; k < 16; k++) {
    int full = (t & 15) | (k << 4) | (wb << 8) | ((t >> 4) << 12);
    wso[bbase + full] = make_float2(ar[k], ai[k]);
  }
}

__device__ __forceinline__ void phaseC_body(int t, int bbase3, int g3,
                                            const float* gsh,
                                            const float2* __restrict__ ws,
                                            float* __restrict__ out) {
  int jt = t | (g3 << 13);
  float br[32], bi[32];
#pragma unroll
  for (int k = 0; k < 32; k++) {
    int j = jt | (k << 8);
    float2 v = ws[bbase3 + fperm(j)];
    br[k] = v.x; bi[k] = v.y;
  }
  greg<1, 1>(br, bi, gsh + (16 + 7) * 8, 0);
  greg<2, 2>(br, bi, gsh + (16 + 6) * 8, 0);
  greg<4, 4>(br, bi, gsh + (16 + 5) * 8, 0);
  greg<8, 8>(br, bi, gsh + (16 + 4) * 8, 0);
  greg<16, 16>(br, bi, gsh + (16 + 3) * 8, 0);
#pragma unroll
  for (int k = 0; k < 32; k++) {
    int j = jt | (k << 8);
    out[bbase3 + finv16(j)] = br[k] * br[k] + bi[k] * bi[k];
  }
}

// ====================== 3-kernel path, rep-counted for diagnostics ======================

__global__ void __launch_bounds__(NT) pass1_k(const float* __restrict__ th,
                                              const float* __restrict__ xre,
                                              const float* __restrict__ xim,
                                              float2* __restrict__ ws,
                                              int reps) {
  __shared__ float gsh[256];
  __shared__ float sre[4096], sim[4096];
  int t = threadIdx.x;
  int blk = blockIdx.x, batch = blk >> 4, wb = blk & 15;
  compute_gates(th, gsh);
  for (int r = 0; r < reps; r++)
    phaseA_body(t, batch * 65536, wb, gsh, sre, sim, xre, xim, ws);
}

__global__ void __launch_bounds__(NT) pass2_k(const float* __restrict__ th,
                                              const float2* __restrict__ wsi,
                                              float2* __restrict__ wso,
                                              int reps) {
  __shared__ float gsh[256];
  __shared__ float sre[4096], sim[4096];
  int t = threadIdx.x;
  int blk = blockIdx.x, batch = blk >> 4, wb = blk & 15;
  compute_gates(th, gsh);
  __syncthreads();   // gsh ready before phaseB reads it
  for (int r = 0; r < reps; r++)
    phaseB_body(t, batch * 65536, wb, gsh, sre, sim, wsi, wso);
}

__global__ void __launch_bounds__(NT) pass3_k(const float* __restrict__ th,
                                              const float2* __restrict__ ws,
                                              float* __restrict__ out,
                                              int reps) {
  __shared__ float gsh[256];
  int t = threadIdx.x;
  int blk = blockIdx.x, batch = blk >> 3, g3 = blk & 7;
  compute_gates(th, gsh);
  __syncthreads();
  for (int r = 0; r < reps; r++)
    phaseC_body(t, batch * 65536, g3, gsh, ws, out);
}

// ====================== Launcher ======================

extern "C" void kernel_launch(void* const* d_in, const int* in_sizes, int n_in,
                              void* d_out, int out_size, void* d_ws, size_t ws_size,
                              hipStream_t stream) {
  const float* th  = (const float*)d_in[0];   // (2,3,16)
  const float* xre = (const float*)d_in[1];   // (32,65536)
  const float* xim = (const float*)d_in[2];   // (32,65536)
  float* out = (float*)d_out;                 // (32,65536) fp32

  float2* amp = (float2*)d_ws;                // 16 MB state

  // Ping-pong target for pass2 (idempotent reps). R9 verified this path
  // (passed, absmax unchanged) => ws_size is large enough on this harness;
  // keep the safety gate anyway.
  bool big = ws_size >= ((size_t)33 << 20);
  float2* amp2 = big ? (float2*)((char*)d_ws + ((size_t)16 << 20)) : amp;
  int reps2 = big ? 3 : 1;

  // R11 diagnostic: reps {3,3,4} so each pass's dispatch (~50-65us) exceeds
  // the 44-47us fill dispatches and surfaces in top-5 with full counters.
  // cold_i = dur_i - (reps_i - 1) * warm_i;  Σcold = 103.8, Σwarm = 29.8 (R9).
  pass1_k<<<512, NT, 0, stream>>>(th, xre, xim, amp, 3);
  pass2_k<<<512, NT, 0, stream>>>(th, amp, amp2, reps2);
  pass3_k<<<256, NT, 0, stream>>>(th, amp2, out, 4);
}

// Round 9
// 105.713 us; speedup vs baseline: 1.4846x; 1.4846x over previous
//
#include <hip/hip_runtime.h>

// 16-qubit, 2-layer circuit, batch 32.  Circuit = P*R1*P*R0 (P = CNOT-ring permutation).
// f(i) = i ^ (i>>1) ^ (bit0(i)?0xC000:0);  f^{-1} = suffix-xor cascade.
//
// R12: PASS1 -> 8 AMPS/THREAD (wave-starvation fix). R11 data: warm bodies are
// ~16us/pass at VALUBusy 44%, occupancy ~10%: 16 amps/thread -> only 2048
// waves -> 2 waves/SIMD (launch-limited; VGPR/LDS irrelevant), so every
// barrier/LDS-latency exposure stalls the SIMD. Memory was exonerated (R10:
// FETCH halved, bench frozen; R11: pass2 FETCH 8MB, still 16us/rep).
// Fix where safe: pass1 has ONLY single-qubit gates -> restructure to 8
// amps/thread, 512-thread blocks: q15-13 in-reg, q12-q7 via __shfl_xor
// butterflies (no barrier), ONE LDS transpose, q6-q4 in-reg. 4096 waves =
// 4 waves/SIMD, barriers 3->2. ws layout identical (linear amp index);
// pass2/pass3 byte-identical to the verified R3/R7 bodies.

#define NT 256

__device__ __forceinline__ int fperm(int x) {
  int y = x ^ (x >> 1);
  y ^= (x & 1) ? 0xC000 : 0;
  return y & 0xFFFF;
}

__device__ __forceinline__ int finv16(int x) {
  int s = x;
  s ^= s >> 1; s ^= s >> 2; s ^= s >> 4; s ^= s >> 8;
  int b15 = ((s ^ (s >> 15)) & 1) << 15;
  return (s & 0x7FFF) | b15;
}

__device__ __forceinline__ int swz1(int l) { return l ^ ((l >> 4) & 31); }
__device__ __forceinline__ int swz2(int l) { return l ^ ((l >> 5) & 31); }

__device__ __forceinline__ void compute_gates(const float* __restrict__ th, float* gsh) {
  int tid = threadIdx.x;
  if (tid < 32) {
    int l = tid >> 4, q = tid & 15;
    float tx = th[l * 48 + q], ty = th[l * 48 + 16 + q], tz = th[l * 48 + 32 + q];
    float cx, sx, cy, sy, cz, sz;
    sincosf(0.5f * tx, &sx, &cx);
    sincosf(0.5f * ty, &sy, &cy);
    sincosf(0.5f * tz, &sz, &cz);
    float m00r = cy * cx, m00i =  sy * sx;
    float m01r = -sy * cx, m01i = -cy * sx;
    float m10r =  sy * cx, m10i = -cy * sx;
    float m11r =  cy * cx, m11i = -sy * sx;
    float* G = gsh + tid * 8;
    G[0] = cz * m00r + sz * m00i;  G[1] = cz * m00i - sz * m00r;
    G[2] = cz * m01r + sz * m01i;  G[3] = cz * m01i - sz * m01r;
    G[4] = cz * m10r - sz * m10i;  G[5] = cz * m10i + sz * m10r;
    G[6] = cz * m11r - sz * m11i;  G[7] = cz * m11i + sz * m11r;
  }
}

template <int MK, int SK, int N>
__device__ __forceinline__ void greg(float (&ar)[N], float (&ai)[N],
                                     const float* G, int c) {
  const float4* G4 = (const float4*)G;
  float4 r0 = G4[0], r1 = G4[1];
  bool sw = (c != 0);
  float h00r = sw ? r1.z : r0.x, h00i = sw ? r1.w : r0.y;
  float h01r = sw ? r1.x : r0.z, h01i = sw ? r1.y : r0.w;
  float h10r = sw ? r0.z : r1.x, h10i = sw ? r0.w : r1.y;
  float h11r = sw ? r0.x : r1.z, h11i = sw ? r0.y : r1.w;
  constexpr int PV = MK & (-MK);
#pragma unroll
  for (int k = 0; k < N; k++) {
    if (k & PV) continue;
    const int k2 = k ^ MK;
    const int p0 = __builtin_popcount(k & SK) & 1;
    const int ka = p0 ? k2 : k;
    const int kb = p0 ? k : k2;
    float xr = ar[ka], xi = ai[ka], yr = ar[kb], yi = ai[kb];
    ar[ka] = h00r * xr - h00i * xi + h01r * yr - h01i * yi;
    ai[ka] = h00r * xi + h00i * xr + h01r * yi + h01i * yr;
    ar[kb] = h10r * xr - h10i * xi + h11r * yr - h11i * yi;
    ai[kb] = h10r * xi + h10i * xr + h11r * yi + h11i * yr;
  }
}

// Cross-lane butterfly on lane-bit mask M (single-qubit gate, amp bit in
// lane space). Low lane holds x, high lane holds y:
//   out_low = h00*x + h01*y ; out_high = h10*x + h11*y
// Each lane: own value + partner via shfl_xor; coeffs selected by side.
template <int M, int N>
__device__ __forceinline__ void gshfl(float (&ar)[N], float (&ai)[N],
                                      const float* G) {
  const float4* G4 = (const float4*)G;
  float4 r0 = G4[0], r1 = G4[1];
  bool hi = (threadIdx.x & M) != 0;
  float hsr = hi ? r1.z : r0.x, hsi = hi ? r1.w : r0.y;  // coeff on own (h11 / h00)
  float hpr = hi ? r1.x : r0.z, hpi = hi ? r1.y : r0.w;  // coeff on partner (h10 / h01)
#pragma unroll
  for (int k = 0; k < N; k++) {
    float pr = __shfl_xor(ar[k], M, 64);
    float pi = __shfl_xor(ai[k], M, 64);
    float vr = ar[k], vi = ai[k];
    ar[k] = hsr * vr - hsi * vi + hpr * pr - hpi * pi;
    ai[k] = hsr * vi + hsi * vr + hpr * pi + hpi * pr;
  }
}

// ====================== Phase bodies (B and C verified, unchanged) ======================

__device__ __forceinline__ void phaseB_body(int t, int bbase, int wb,
                                            const float* gsh,
                                            float* sre, float* sim,
                                            float2* __restrict__ ws) {
  float ar[16], ai[16];
#pragma unroll
  for (int k = 0; k < 16; k++) {
    float2 v = ws[bbase + t + (wb << 8) + (k << 12)];
    ar[k] = v.x; ai[k] = v.y;
  }
  int cA = (__popc(t) + __popc(wb)) & 1;   // parity of full bits 0..11
  greg<1, 1>(ar, ai, gsh + 3 * 8, 0);
  greg<2, 2>(ar, ai, gsh + 2 * 8, 0);
  greg<4, 4>(ar, ai, gsh + 1 * 8, 0);
  greg<8, 8>(ar, ai, gsh + 0 * 8, 0);
  greg<12, 7>(ar, ai, gsh + (16 + 0) * 8, cA);
  greg<6, 12>(ar, ai, gsh + (16 + 1) * 8, 0);
  greg<3, 14>(ar, ai, gsh + (16 + 2) * 8, 0);
  __syncthreads();   // sre/sim free
#pragma unroll
  for (int k = 0; k < 16; k++) {
    int s = swz2(t | (k << 8)); sre[s] = ar[k]; sim[s] = ai[k];
  }
  __syncthreads();
#pragma unroll
  for (int k = 0; k < 16; k++) {
    int s = swz2((k & 3) | (t << 2) | ((k >> 2) << 10));
    ar[k] = sre[s]; ai[k] = sim[s];
  }
  greg<13, 15>(ar, ai, gsh + (16 + 15) * 8, cA);
  greg<3, 14>(ar, ai, gsh + (16 + 14) * 8, cA);
#pragma unroll
  for (int k = 0; k < 16; k++) {
    int s = swz2((k & 3) | (t << 2) | ((k >> 2) << 10));
    sre[s] = ar[k]; sim[s] = ai[k];
  }
  __syncthreads();
#pragma unroll
  for (int k = 0; k < 16; k++) {
    int s = swz2((t & 1) | (k << 1) | ((t >> 1) << 5));
    ar[k] = sre[s]; ai[k] = sim[s];
  }
  {
    int cC = (__popc(t >> 1) + __popc(wb)) & 1;
    greg<3, 14>(ar, ai, gsh + (16 + 13) * 8, cC);
    greg<6, 12>(ar, ai, gsh + (16 + 12) * 8, cC);
    greg<12, 8>(ar, ai, gsh + (16 + 11) * 8, cC);
  }
#pragma unroll
  for (int k = 0; k < 16; k++) {
    int s = swz2((t & 1) | (k << 1) | ((t >> 1) << 5));
    sre[s] = ar[k]; sim[s] = ai[k];
  }
  __syncthreads();
#pragma unroll
  for (int k = 0; k < 16; k++) {
    int s = swz2((t & 15) | (k << 4) | ((t >> 4) << 8));
    ar[k] = sre[s]; ai[k] = sim[s];
  }
  {
    int cD = (__popc(t >> 4) + __popc(wb)) & 1;
    greg<3, 14>(ar, ai, gsh + (16 + 10) * 8, cD);
    greg<6, 12>(ar, ai, gsh + (16 + 9) * 8, cD);
    greg<12, 8>(ar, ai, gsh + (16 + 8) * 8, cD);
  }
#pragma unroll
  for (int k = 0; k < 16; k++) {
    int full = (t & 15) | (k << 4) | (wb << 8) | ((t >> 4) << 12);
    ws[bbase + full] = make_float2(ar[k], ai[k]);
  }
}

__device__ __forceinline__ void phaseC_body(int t, int bbase3, int g3,
                                            const float* gsh,
                                            const float2* __restrict__ ws,
                                            float* __restrict__ out) {
  int jt = t | (g3 << 13);
  float br[32], bi[32];
#pragma unroll
  for (int k = 0; k < 32; k++) {
    int j = jt | (k << 8);
    float2 v = ws[bbase3 + fperm(j)];
    br[k] = v.x; bi[k] = v.y;
  }
  greg<1, 1>(br, bi, gsh + (16 + 7) * 8, 0);
  greg<2, 2>(br, bi, gsh + (16 + 6) * 8, 0);
  greg<4, 4>(br, bi, gsh + (16 + 5) * 8, 0);
  greg<8, 8>(br, bi, gsh + (16 + 4) * 8, 0);
  greg<16, 16>(br, bi, gsh + (16 + 3) * 8, 0);
#pragma unroll
  for (int k = 0; k < 32; k++) {
    int j = jt | (k << 8);
    out[bbase3 + finv16(j)] = br[k] * br[k] + bi[k] * bi[k];
  }
}

// ====================== pass1: NEW 8-amp/thread structure ======================
//
// 512 threads/block, 8 amps/thread, 512 blocks -> 4096 waves (4/SIMD).
// Amp index bits: k(reg)=0..2, t=3..11 (lane=bits 3..8, wave=bits 9..11),
// wb=12..15.  Gates (qubit q acts on bit 15-q):
//   q15,q14,q13 -> reg masks 1,2,4
//   q12..q7     -> lane-bit shuffles M=1,2,4,8,16,32
//   q6,q5,q4    -> after one LDS transpose (reg bits <-> bits 9..11)
// Output: linear amp layout, identical to what phaseB expects.

__global__ void __launch_bounds__(512) pass1_k(const float* __restrict__ th,
                                               const float* __restrict__ xre,
                                               const float* __restrict__ xim,
                                               float2* __restrict__ ws) {
  __shared__ float gsh[256];
  __shared__ float sre[4096], sim[4096];
  int t = threadIdx.x;                       // 0..511 = amp bits 3..11
  int blk = blockIdx.x, batch = blk >> 4, wb = blk & 15;
  int base = batch * 65536 + (wb << 12);

  compute_gates(th, gsh);

  float ar[8], ai[8];
  const float4* xr4 = (const float4*)(xre + base + (t << 3));
  const float4* xi4 = (const float4*)(xim + base + (t << 3));
  {
    float4 v0 = xr4[0], v1 = xr4[1];
    float4 w0 = xi4[0], w1 = xi4[1];
    ar[0] = v0.x; ar[1] = v0.y; ar[2] = v0.z; ar[3] = v0.w;
    ar[4] = v1.x; ar[5] = v1.y; ar[6] = v1.z; ar[7] = v1.w;
    ai[0] = w0.x; ai[1] = w0.y; ai[2] = w0.z; ai[3] = w0.w;
    ai[4] = w1.x; ai[5] = w1.y; ai[6] = w1.z; ai[7] = w1.w;
  }
  __syncthreads();   // gsh ready

  // q15,q14,q13 on reg bits 0,1,2
  greg<1, 1>(ar, ai, gsh + 15 * 8, 0);
  greg<2, 2>(ar, ai, gsh + 14 * 8, 0);
  greg<4, 4>(ar, ai, gsh + 13 * 8, 0);

  // q12..q7 on lane bits 0..5 (amp bits 3..8) — no barriers
  gshfl<1> (ar, ai, gsh + 12 * 8);
  gshfl<2> (ar, ai, gsh + 11 * 8);
  gshfl<4> (ar, ai, gsh + 10 * 8);
  gshfl<8> (ar, ai, gsh + 9 * 8);
  gshfl<16>(ar, ai, gsh + 8 * 8);
  gshfl<32>(ar, ai, gsh + 7 * 8);

  // one LDS transpose: reg bits (0..2) <-> amp bits 9..11
#pragma unroll
  for (int k = 0; k < 8; k++) {
    int s = swz1((t << 3) | k);
    sre[s] = ar[k]; sim[s] = ai[k];
  }
  __syncthreads();
#pragma unroll
  for (int k = 0; k < 8; k++) {
    int s = swz1(t | (k << 9));
    ar[k] = sre[s]; ai[k] = sim[s];
  }

  // q6,q5,q4 on (new) reg bits = amp bits 9,10,11
  greg<1, 1>(ar, ai, gsh + 6 * 8, 0);
  greg<2, 2>(ar, ai, gsh + 5 * 8, 0);
  greg<4, 4>(ar, ai, gsh + 4 * 8, 0);

#pragma unroll
  for (int k = 0; k < 8; k++)
    ws[base + (t | (k << 9))] = make_float2(ar[k], ai[k]);
}

// ====================== pass2/pass3 (verified, unchanged) ======================

__global__ void __launch_bounds__(NT) pass2_k(const float* __restrict__ th,
                                              float2* __restrict__ ws) {
  __shared__ float gsh[256];
  __shared__ float sre[4096], sim[4096];
  int t = threadIdx.x;
  int blk = blockIdx.x, batch = blk >> 4, wb = blk & 15;
  compute_gates(th, gsh);
  __syncthreads();   // gsh ready before phaseB reads it
  phaseB_body(t, batch * 65536, wb, gsh, sre, sim, ws);
}

__global__ void __launch_bounds__(NT) pass3_k(const float* __restrict__ th,
                                              const float2* __restrict__ ws,
                                              float* __restrict__ out) {
  __shared__ float gsh[256];
  int t = threadIdx.x;
  int blk = blockIdx.x, batch = blk >> 3, g3 = blk & 7;
  compute_gates(th, gsh);
  __syncthreads();
  phaseC_body(t, batch * 65536, g3, gsh, ws, out);
}

// ====================== Launcher ======================

extern "C" void kernel_launch(void* const* d_in, const int* in_sizes, int n_in,
                              void* d_out, int out_size, void* d_ws, size_t ws_size,
                              hipStream_t stream) {
  const float* th  = (const float*)d_in[0];   // (2,3,16)
  const float* xre = (const float*)d_in[1];   // (32,65536)
  const float* xim = (const float*)d_in[2];   // (32,65536)
  float* out = (float*)d_out;                 // (32,65536) fp32

  float2* amp = (float2*)d_ws;                // 16 MB state

  pass1_k<<<512, 512, 0, stream>>>(th, xre, xim, amp);
  pass2_k<<<512, NT, 0, stream>>>(th, amp);
  pass3_k<<<256, NT, 0, stream>>>(th, amp, out);
}

// Round 10
// 104.462 us; speedup vs baseline: 1.5024x; 1.0120x over previous
//
#include <hip/hip_runtime.h>

// 16-qubit, 2-layer circuit, batch 32.  Circuit = P*R1*P*R0 (P = CNOT-ring permutation).
// f(i) = i ^ (i>>1) ^ (bit0(i)?0xC000:0);  f^{-1} = suffix-xor cascade.
//
// R13: CROSS-BATCH CO-RESIDENCY PAIRING on the verified R10 fused kernel.
// Model (R11 counters): warm bodies are VALU-dependency-bound (~7us pure
// VALU-issue/pass, ~2x stall factor at 2 waves/SIMD); R10 proved consumer
// reads L2-hit (FETCH halved) and profiled-max 89.8 < bench 105.6 proves a
// harness floor >= ~16us. Remaining kernel lever: fill dependency-stall and
// spin-wait windows with INDEPENDENT work. HW round-robin dispatch co-locates
// blk and blk+256 on one CU; R10's map gave them the SAME batch -> lockstep.
// New map routes bit8 into the batch index: co-resident blocks = DIFFERENT
// batches -> cross-phase overlap, effective 4 waves/SIMD. XCD pinning (batch
// -> one XCD) preserved; fence-skip still runtime-verified via XCC_ID mask.

#define NT 256

__device__ __forceinline__ int fperm(int x) {
  int y = x ^ (x >> 1);
  y ^= (x & 1) ? 0xC000 : 0;
  return y & 0xFFFF;
}

__device__ __forceinline__ int finv16(int x) {
  int s = x;
  s ^= s >> 1; s ^= s >> 2; s ^= s >> 4; s ^= s >> 8;
  int b15 = ((s ^ (s >> 15)) & 1) << 15;
  return (s & 0x7FFF) | b15;
}

__device__ __forceinline__ int swz1(int l) { return l ^ ((l >> 4) & 31); }
__device__ __forceinline__ int swz2(int l) { return l ^ ((l >> 5) & 31); }

__device__ __forceinline__ void compute_gates(const float* __restrict__ th, float* gsh) {
  int tid = threadIdx.x;
  if (tid < 32) {
    int l = tid >> 4, q = tid & 15;
    float tx = th[l * 48 + q], ty = th[l * 48 + 16 + q], tz = th[l * 48 + 32 + q];
    float cx, sx, cy, sy, cz, sz;
    sincosf(0.5f * tx, &sx, &cx);
    sincosf(0.5f * ty, &sy, &cy);
    sincosf(0.5f * tz, &sz, &cz);
    float m00r = cy * cx, m00i =  sy * sx;
    float m01r = -sy * cx, m01i = -cy * sx;
    float m10r =  sy * cx, m10i = -cy * sx;
    float m11r =  cy * cx, m11i = -sy * sx;
    float* G = gsh + tid * 8;
    G[0] = cz * m00r + sz * m00i;  G[1] = cz * m00i - sz * m00r;
    G[2] = cz * m01r + sz * m01i;  G[3] = cz * m01i - sz * m01r;
    G[4] = cz * m10r - sz * m10i;  G[5] = cz * m10i + sz * m10r;
    G[6] = cz * m11r - sz * m11i;  G[7] = cz * m11i + sz * m11r;
  }
}

template <int MK, int SK, int N>
__device__ __forceinline__ void greg(float (&ar)[N], float (&ai)[N],
                                     const float* G, int c) {
  const float4* G4 = (const float4*)G;
  float4 r0 = G4[0], r1 = G4[1];
  bool sw = (c != 0);
  float h00r = sw ? r1.z : r0.x, h00i = sw ? r1.w : r0.y;
  float h01r = sw ? r1.x : r0.z, h01i = sw ? r1.y : r0.w;
  float h10r = sw ? r0.z : r1.x, h10i = sw ? r0.w : r1.y;
  float h11r = sw ? r0.x : r1.z, h11i = sw ? r0.y : r1.w;
  constexpr int PV = MK & (-MK);
#pragma unroll
  for (int k = 0; k < N; k++) {
    if (k & PV) continue;
    const int k2 = k ^ MK;
    const int p0 = __builtin_popcount(k & SK) & 1;
    const int ka = p0 ? k2 : k;
    const int kb = p0 ? k : k2;
    float xr = ar[ka], xi = ai[ka], yr = ar[kb], yi = ai[kb];
    ar[ka] = h00r * xr - h00i * xi + h01r * yr - h01i * yi;
    ai[ka] = h00r * xi + h00i * xr + h01r * yi + h01i * yr;
    ar[kb] = h10r * xr - h10i * xi + h11r * yr - h11i * yi;
    ai[kb] = h10r * xi + h10i * xr + h11r * yi + h11i * yr;
  }
}

// ====================== Phase bodies as device functions ======================

__device__ __forceinline__ void phaseA_body(int t, int bbase, int wb,
                                            const float* gsh,
                                            float* sre, float* sim,
                                            const float* __restrict__ xre,
                                            const float* __restrict__ xim,
                                            float2* __restrict__ ws) {
  float ar[16], ai[16];
  int base = bbase + (wb << 12);
  const float4* xr4 = (const float4*)(xre + base + (t << 4));
  const float4* xi4 = (const float4*)(xim + base + (t << 4));
#pragma unroll
  for (int q = 0; q < 4; q++) {
    float4 v = xr4[q]; ar[4*q] = v.x; ar[4*q+1] = v.y; ar[4*q+2] = v.z; ar[4*q+3] = v.w;
    float4 w = xi4[q]; ai[4*q] = w.x; ai[4*q+1] = w.y; ai[4*q+2] = w.z; ai[4*q+3] = w.w;
  }
  __syncthreads();   // gsh ready (and sre/sim free)
  greg<1, 1>(ar, ai, gsh + 15 * 8, 0);
  greg<2, 2>(ar, ai, gsh + 14 * 8, 0);
  greg<4, 4>(ar, ai, gsh + 13 * 8, 0);
  greg<8, 8>(ar, ai, gsh + 12 * 8, 0);
#pragma unroll
  for (int k = 0; k < 16; k++) { int s = swz1((t << 4) | k); sre[s] = ar[k]; sim[s] = ai[k]; }
  __syncthreads();
#pragma unroll
  for (int k = 0; k < 16; k++) {
    int s = swz1((t & 15) | (k << 4) | ((t >> 4) << 8));
    ar[k] = sre[s]; ai[k] = sim[s];
  }
  greg<1, 1>(ar, ai, gsh + 11 * 8, 0);
  greg<2, 2>(ar, ai, gsh + 10 * 8, 0);
  greg<4, 4>(ar, ai, gsh + 9 * 8, 0);
  greg<8, 8>(ar, ai, gsh + 8 * 8, 0);
#pragma unroll
  for (int k = 0; k < 16; k++) {
    int s = swz1((t & 15) | (k << 4) | ((t >> 4) << 8));
    sre[s] = ar[k]; sim[s] = ai[k];
  }
  __syncthreads();
#pragma unroll
  for (int k = 0; k < 16; k++) {
    int s = swz1(t | (k << 8)); ar[k] = sre[s]; ai[k] = sim[s];
  }
  greg<1, 1>(ar, ai, gsh + 7 * 8, 0);
  greg<2, 2>(ar, ai, gsh + 6 * 8, 0);
  greg<4, 4>(ar, ai, gsh + 5 * 8, 0);
  greg<8, 8>(ar, ai, gsh + 4 * 8, 0);
#pragma unroll
  for (int k = 0; k < 16; k++)
    ws[base + t + (k << 8)] = make_float2(ar[k], ai[k]);
}

__device__ __forceinline__ void phaseB_body(int t, int bbase, int wb,
                                            const float* gsh,
                                            float* sre, float* sim,
                                            float2* __restrict__ ws) {
  float ar[16], ai[16];
#pragma unroll
  for (int k = 0; k < 16; k++) {
    float2 v = ws[bbase + t + (wb << 8) + (k << 12)];
    ar[k] = v.x; ai[k] = v.y;
  }
  int cA = (__popc(t) + __popc(wb)) & 1;   // parity of full bits 0..11
  greg<1, 1>(ar, ai, gsh + 3 * 8, 0);
  greg<2, 2>(ar, ai, gsh + 2 * 8, 0);
  greg<4, 4>(ar, ai, gsh + 1 * 8, 0);
  greg<8, 8>(ar, ai, gsh + 0 * 8, 0);
  greg<12, 7>(ar, ai, gsh + (16 + 0) * 8, cA);
  greg<6, 12>(ar, ai, gsh + (16 + 1) * 8, 0);
  greg<3, 14>(ar, ai, gsh + (16 + 2) * 8, 0);
  __syncthreads();   // sre/sim free
#pragma unroll
  for (int k = 0; k < 16; k++) {
    int s = swz2(t | (k << 8)); sre[s] = ar[k]; sim[s] = ai[k];
  }
  __syncthreads();
#pragma unroll
  for (int k = 0; k < 16; k++) {
    int s = swz2((k & 3) | (t << 2) | ((k >> 2) << 10));
    ar[k] = sre[s]; ai[k] = sim[s];
  }
  greg<13, 15>(ar, ai, gsh + (16 + 15) * 8, cA);
  greg<3, 14>(ar, ai, gsh + (16 + 14) * 8, cA);
#pragma unroll
  for (int k = 0; k < 16; k++) {
    int s = swz2((k & 3) | (t << 2) | ((k >> 2) << 10));
    sre[s] = ar[k]; sim[s] = ai[k];
  }
  __syncthreads();
#pragma unroll
  for (int k = 0; k < 16; k++) {
    int s = swz2((t & 1) | (k << 1) | ((t >> 1) << 5));
    ar[k] = sre[s]; ai[k] = sim[s];
  }
  {
    int cC = (__popc(t >> 1) + __popc(wb)) & 1;
    greg<3, 14>(ar, ai, gsh + (16 + 13) * 8, cC);
    greg<6, 12>(ar, ai, gsh + (16 + 12) * 8, cC);
    greg<12, 8>(ar, ai, gsh + (16 + 11) * 8, cC);
  }
#pragma unroll
  for (int k = 0; k < 16; k++) {
    int s = swz2((t & 1) | (k << 1) | ((t >> 1) << 5));
    sre[s] = ar[k]; sim[s] = ai[k];
  }
  __syncthreads();
#pragma unroll
  for (int k = 0; k < 16; k++) {
    int s = swz2((t & 15) | (k << 4) | ((t >> 4) << 8));
    ar[k] = sre[s]; ai[k] = sim[s];
  }
  {
    int cD = (__popc(t >> 4) + __popc(wb)) & 1;
    greg<3, 14>(ar, ai, gsh + (16 + 10) * 8, cD);
    greg<6, 12>(ar, ai, gsh + (16 + 9) * 8, cD);
    greg<12, 8>(ar, ai, gsh + (16 + 8) * 8, cD);
  }
#pragma unroll
  for (int k = 0; k < 16; k++) {
    int full = (t & 15) | (k << 4) | (wb << 8) | ((t >> 4) << 12);
    ws[bbase + full] = make_float2(ar[k], ai[k]);
  }
}

__device__ __forceinline__ void phaseC_body(int t, int bbase3, int g3,
                                            const float* gsh,
                                            const float2* __restrict__ ws,
                                            float* __restrict__ out) {
  int jt = t | (g3 << 13);
  float br[32], bi[32];
#pragma unroll
  for (int k = 0; k < 32; k++) {
    int j = jt | (k << 8);
    float2 v = ws[bbase3 + fperm(j)];
    br[k] = v.x; bi[k] = v.y;
  }
  greg<1, 1>(br, bi, gsh + (16 + 7) * 8, 0);
  greg<2, 2>(br, bi, gsh + (16 + 6) * 8, 0);
  greg<4, 4>(br, bi, gsh + (16 + 5) * 8, 0);
  greg<8, 8>(br, bi, gsh + (16 + 4) * 8, 0);
  greg<16, 16>(br, bi, gsh + (16 + 3) * 8, 0);
#pragma unroll
  for (int k = 0; k < 32; k++) {
    int j = jt | (k << 8);
    out[bbase3 + finv16(j)] = br[k] * br[k] + bi[k] * bi[k];
  }
}

// ====================== Fallback: verified R3 three-kernel path ======================

__global__ void __launch_bounds__(NT) pass1_k(const float* __restrict__ th,
                                              const float* __restrict__ xre,
                                              const float* __restrict__ xim,
                                              float2* __restrict__ ws) {
  __shared__ float gsh[256];
  __shared__ float sre[4096], sim[4096];
  int t = threadIdx.x;
  int blk = blockIdx.x, batch = blk >> 4, wb = blk & 15;
  compute_gates(th, gsh);
  phaseA_body(t, batch * 65536, wb, gsh, sre, sim, xre, xim, ws);
}

__global__ void __launch_bounds__(NT) pass2_k(const float* __restrict__ th,
                                              float2* __restrict__ ws) {
  __shared__ float gsh[256];
  __shared__ float sre[4096], sim[4096];
  int t = threadIdx.x;
  int blk = blockIdx.x, batch = blk >> 4, wb = blk & 15;
  compute_gates(th, gsh);
  __syncthreads();   // gsh ready before phaseB reads it
  phaseB_body(t, batch * 65536, wb, gsh, sre, sim, ws);
}

__global__ void __launch_bounds__(NT) pass3_k(const float* __restrict__ th,
                                              const float2* __restrict__ ws,
                                              float* __restrict__ out) {
  __shared__ float gsh[256];
  int t = threadIdx.x;
  int blk = blockIdx.x, batch = blk >> 3, g3 = blk & 7;
  compute_gates(th, gsh);
  __syncthreads();
  phaseC_body(t, batch * 65536, g3, gsh, ws, out);
}

// ====================== Fused kernel (spin-sync, XCD-local, cross-batch paired) ======================

__device__ __forceinline__ void signal(unsigned* cnt, unsigned* msk, unsigned xcd) {
  __threadfence_block();
  __syncthreads();
  if (threadIdx.x == 0) {
    __hip_atomic_fetch_or(msk, 1u << (xcd & 31), __ATOMIC_RELAXED, __HIP_MEMORY_SCOPE_AGENT);
    __hip_atomic_fetch_add(cnt, 1u, __ATOMIC_RELEASE, __HIP_MEMORY_SCOPE_AGENT);
  }
}

__device__ __forceinline__ void wait16(unsigned* cnt, unsigned* msk, unsigned* sflag) {
  if (threadIdx.x == 0) {
    while (__hip_atomic_load(cnt, __ATOMIC_RELAXED, __HIP_MEMORY_SCOPE_AGENT) < 16u)
      __builtin_amdgcn_s_sleep(2);
    unsigned m = __hip_atomic_load(msk, __ATOMIC_RELAXED, __HIP_MEMORY_SCOPE_AGENT);
    *sflag = ((m & (m - 1u)) == 0u) ? 1u : 0u;
  }
  __syncthreads();
  if (*sflag == 0u)
    __builtin_amdgcn_fence(__ATOMIC_ACQUIRE, "agent");
}

__global__ void __launch_bounds__(NT, 2)
fused_k(const float* __restrict__ th,
        const float* __restrict__ xre, const float* __restrict__ xim,
        float2* __restrict__ ws, float* __restrict__ out,
        unsigned* __restrict__ sync) {
  __shared__ float gsh[256];
  __shared__ float sre[4096], sim[4096];
  __shared__ unsigned sflag;
  int t = threadIdx.x;
  int blk = blockIdx.x;

  // R13 map: blk bits [b8][b7..b4][b3][b2..b0].
  //   batch = (b2..b0)*4 + b3*2 + b8   (XCD-pinned: all blocks of a batch share
  //                                     b2..b0 = HW round-robin XCD)
  //   wb    = b7..b4
  // Co-residency: HW places blk and blk+256 on the same CU (round-robin wrap);
  // they differ in b8 -> DIFFERENT batches -> cross-batch phase overlap fills
  // VALU-dependency stalls and spin-wait windows. Bijection: 8x2x2x16 = 512.
  int xcd_hint = blk & 7;
  int batch = xcd_hint * 4 + (((blk >> 3) & 1) << 1) + ((blk >> 8) & 1);
  int wb = (blk >> 4) & 15;
  int bbase = batch * 65536;

  unsigned xcc;
  asm volatile("s_getreg_b32 %0, hwreg(HW_REG_XCC_ID)" : "=s"(xcc));

  unsigned* cnt1 = sync;        // [0..31]
  unsigned* msk1 = sync + 32;   // [32..63]
  unsigned* cnt2 = sync + 64;   // [64..95]
  unsigned* msk2 = sync + 96;   // [96..127]

  compute_gates(th, gsh);
  phaseA_body(t, bbase, wb, gsh, sre, sim, xre, xim, ws);
  signal(&cnt1[batch], &msk1[batch], xcc);

  wait16(&cnt1[batch], &msk1[batch], &sflag);
  phaseB_body(t, bbase, wb, gsh, sre, sim, ws);
  signal(&cnt2[batch], &msk2[batch], xcc);

  if (blk >= 256) return;
  // Phase C mapping (blocks 0..255): batch3 = (blk&7)*4 + ((blk>>3)&3) keeps
  // reader XCD == writer XCD (batch3>>2 == blk&7); g3 = blk>>5 in 0..7.
  int batch3 = (blk & 7) * 4 + ((blk >> 3) & 3), g3 = blk >> 5;
  wait16(&cnt2[batch3], &msk2[batch3], &sflag);
  phaseC_body(t, batch3 * 65536, g3, gsh, ws, out);
}

// ====================== Launcher ======================

extern "C" void kernel_launch(void* const* d_in, const int* in_sizes, int n_in,
                              void* d_out, int out_size, void* d_ws, size_t ws_size,
                              hipStream_t stream) {
  const float* th  = (const float*)d_in[0];   // (2,3,16)
  const float* xre = (const float*)d_in[1];   // (32,65536)
  const float* xim = (const float*)d_in[2];   // (32,65536)
  float* out = (float*)d_out;                 // (32,65536) fp32

  float2* amp = (float2*)d_ws;                              // 16 MB state
  unsigned* sync = (unsigned*)((char*)d_ws + (16u << 20));  // 128 u32 counters/masks

  int maxBlk = 0;
  hipError_t qrc = hipOccupancyMaxActiveBlocksPerMultiprocessor(
      &maxBlk, (const void*)fused_k, NT, 0);
  bool use_fused = (qrc == hipSuccess && maxBlk >= 2);

  if (use_fused) {
    hipMemsetAsync((void*)sync, 0, 128 * sizeof(unsigned), stream);
    fused_k<<<512, NT, 0, stream>>>(th, xre, xim, amp, out, sync);
  } else {
    // Verified R3 path.
    pass1_k<<<512, NT, 0, stream>>>(th, xre, xim, amp);
    pass2_k<<<512, NT, 0, stream>>>(th, amp);
    pass3_k<<<256, NT, 0, stream>>>(th, amp, out);
  }
}